// Round 2
// baseline (633.255 us; speedup 1.0000x reference)
//
#include <hip/hip_runtime.h>
#include <math.h>

#define FDIM 256
#define NH 8
#define HD 32
#define NQ 4096
#define NKEY 4096
#define CAP 512
#define R2 9.0f
#define NBLK 1024  // 256 CUs x 4 blocks/CU: guaranteed co-resident with
                   // __launch_bounds__(256,4) (VGPR<=128), LDS 6KB, 16 waves/CU

typedef _Float16 half8 __attribute__((ext_vector_type(8)));
typedef _Float16 half4v __attribute__((ext_vector_type(4)));
typedef float f32x4 __attribute__((ext_vector_type(4)));
typedef unsigned short ushort_t;

// castbuf layout (f16 elements)
#define CB_CUR  0
#define CB_HIST 1048576
#define CB_WQ   2097152
#define CB_WK   2162688
#define CB_WV   2228224
#define CB_WO   2293760
#define CB_F4_TOTAL 589824  // total float4 groups (2359296 floats / 4)

// ---------------------------------------------------------------------------
// Device-scope grid barrier for a persistent 1024-block grid.
// Two-level atomic tree (8 leaves x 128 blocks -> root) to avoid 1024-way
// same-address atomic serialization; agent-scope release/acquire on the flag
// plus __threadfence() (agent fence: L2 writeback/invalidate) so phase data
// is visible across non-coherent per-XCD L2s (G16).
// Layout per phase: ints [0..7]=leaf counters, [8]=root, [9]=flag.
// ---------------------------------------------------------------------------
__device__ __forceinline__ void gridbar(int* bar, int ph) {
    __syncthreads();
    if (threadIdx.x == 0) {
        __threadfence();  // release: make this block's stores device-visible
        int* base = bar + ph * 12;
        const int leaf = blockIdx.x & 7;
        if (atomicAdd(base + leaf, 1) == (NBLK / 8) - 1) {
            if (atomicAdd(base + 8, 1) == 7) {
                __hip_atomic_store(base + 9, 1, __ATOMIC_RELEASE,
                                   __HIP_MEMORY_SCOPE_AGENT);
            }
        }
        while (__hip_atomic_load(base + 9, __ATOMIC_ACQUIRE,
                                 __HIP_MEMORY_SCOPE_AGENT) == 0)
            __builtin_amdgcn_s_sleep(8);
        __threadfence();  // acquire: invalidate stale local cache lines
    }
    __syncthreads();
}

// ---------------------------------------------------------------------------
// MFMA GEMM core: C[m][n] = sum_k A[m][k] * W[n][k]  (f16 row-major, K=256).
// Wave tile 16x64, no LDS. A-frag A[m=lane&15][k=quad*8+j]; B-frag = 8
// contiguous f16 of a W row. C/D: row=quad*4+r, col=lane&15.
// ---------------------------------------------------------------------------
__device__ __forceinline__ void mfma_tile_16x64(const _Float16* __restrict__ A,
                                                const _Float16* __restrict__ W,
                                                int m0, int n0, int wave, int lane,
                                                f32x4 acc[4]) {
    const int row  = lane & 15;
    const int quad = lane >> 4;
    const _Float16* aptr = A + (size_t)(m0 + wave * 16 + row) * 256 + quad * 8;
    const _Float16* wptr = W + (size_t)(n0 + row) * 256 + quad * 8;
#pragma unroll
    for (int i = 0; i < 4; ++i) acc[i] = (f32x4){0.f, 0.f, 0.f, 0.f};
#pragma unroll
    for (int k0 = 0; k0 < 8; ++k0) {
        half8 a = *(const half8*)(aptr + k0 * 32);
#pragma unroll
        for (int nt = 0; nt < 4; ++nt) {
            half8 b = *(const half8*)(wptr + (size_t)nt * 16 * 256 + k0 * 32);
            acc[nt] = __builtin_amdgcn_mfma_f32_16x16x32_f16(a, b, acc[nt], 0, 0, 0);
        }
    }
}

// ---------------------------------------------------------------------------
// One persistent kernel, 4 phases separated by grid barriers:
//   A: neighbor lists (exact ref fp32 order) + fp32->fp16 cast of GEMM inputs
//   B: QKV projection GEMMs (768 tiles on blocks 0..767)
//   C: sparse attention (4 queries per block, v9 math: shift-free softmax)
//   D: O projection (256 tiles on blocks 0..255)
// Fusing removes 3 launch gaps and, critically, produces ONE dispatch whose
// rocprof counters (dur/MfmaUtil/VALUBusy/FETCH) are visible above the
// harness's 41us re-poison fills in the top-5 table.
// ---------------------------------------------------------------------------
__global__ __launch_bounds__(256, 4) void fused(
    const float* __restrict__ cur,  const float* __restrict__ histf,
    const float* __restrict__ Wq,   const float* __restrict__ Wk,
    const float* __restrict__ Wv,   const float* __restrict__ Wo,
    const float* __restrict__ qc,   const float* __restrict__ kc,
    const float* __restrict__ bq,   const float* __restrict__ bk,
    const float* __restrict__ bv,   const float* __restrict__ bo,
    _Float16* __restrict__ cb,      _Float16* __restrict__ Qh,
    _Float16* __restrict__ KV,      ushort_t* __restrict__ nbr,
    int* __restrict__ cnt,          _Float16* __restrict__ Ob,
    float* __restrict__ out,        int* __restrict__ bar) {
    __shared__ float sm[4][32][12];
    const int b    = blockIdx.x;
    const int t    = threadIdx.x;
    const int wave = t >> 6;
    const int lane = t & 63;

    // ================= Phase A: neighbors + cast =================
    {
        // neighbor build: exact reference fp32 op order (no contraction)
        const int q  = b * 4 + wave;
        const float qx = qc[q * 3 + 0];
        const float qy = qc[q * 3 + 1];
        const float qz = qc[q * 3 + 2];
        int base = 0;
        for (int k0 = 0; k0 < NKEY; k0 += 64) {
            const int k = k0 + lane;
            float dx = __fsub_rn(qx, kc[k * 3 + 0]);
            float dy = __fsub_rn(qy, kc[k * 3 + 1]);
            float dz = __fsub_rn(qz, kc[k * 3 + 2]);
            float d2 = __fadd_rn(__fadd_rn(__fmul_rn(dx, dx), __fmul_rn(dy, dy)),
                                 __fmul_rn(dz, dz));
            bool valid = (d2 <= R2);
            unsigned long long bal = __ballot(valid);
            if (valid) {
                int pos = base + __popcll(bal & ((1ull << lane) - 1ull));
                if (pos < CAP) nbr[(size_t)q * CAP + pos] = (ushort_t)k;
            }
            base += __popcll(bal);
        }
        if (lane == 0) cnt[q] = (base > CAP) ? CAP : base;

        // fp32 -> fp16 cast of feats + weights (grid-stride over all blocks)
        for (int i4 = b * 256 + t; i4 < CB_F4_TOTAL; i4 += NBLK * 256) {
            const float* src;
            int boff;
            if (i4 < 262144)      { src = cur;   boff = 0; }
            else if (i4 < 524288) { src = histf; boff = 262144; }
            else if (i4 < 540672) { src = Wq;    boff = 524288; }
            else if (i4 < 557056) { src = Wk;    boff = 540672; }
            else if (i4 < 573440) { src = Wv;    boff = 557056; }
            else                  { src = Wo;    boff = 573440; }
            float4 v = ((const float4*)src)[i4 - boff];
            half4v h;
            h[0] = (_Float16)v.x; h[1] = (_Float16)v.y;
            h[2] = (_Float16)v.z; h[3] = (_Float16)v.w;
            ((half4v*)cb)[i4] = h;
        }
    }
    gridbar(bar, 0);

    // ================= Phase B: QKV GEMMs =================
    if (b < 768) {
        const int z   = b >> 8;        // 0:Q 1:K 2:V
        const int rem = b & 255;
        const int m0  = (rem >> 2) * 64;
        const int n0  = (rem & 3) * 64;

        const _Float16* A = (z == 0) ? (cb + CB_CUR) : (cb + CB_HIST);
        const _Float16* W = (z == 0) ? (cb + CB_WQ)
                          : (z == 1) ? (cb + CB_WK) : (cb + CB_WV);
        const float* bias = (z == 0) ? bq : (z == 1) ? bk : bv;

        f32x4 acc[4];
        mfma_tile_16x64(A, W, m0, n0, wave, lane, acc);

        const int col  = lane & 15;
        const int quad = lane >> 4;
        float bs[4];
#pragma unroll
        for (int nt = 0; nt < 4; ++nt) bs[nt] = bias[n0 + nt * 16 + col];

        if (z == 0) {
#pragma unroll
            for (int nt = 0; nt < 4; ++nt)
#pragma unroll
                for (int r = 0; r < 4; ++r)
                    Qh[(size_t)(m0 + wave * 16 + quad * 4 + r) * 256 +
                       n0 + nt * 16 + col] = (_Float16)(acc[nt][r] + bs[nt]);
        } else {
            const int off = (z == 1) ? 0 : 256;
#pragma unroll
            for (int nt = 0; nt < 4; ++nt)
#pragma unroll
                for (int r = 0; r < 4; ++r)
                    KV[(size_t)(m0 + wave * 16 + quad * 4 + r) * 512 + off +
                       n0 + nt * 16 + col] = (_Float16)(acc[nt][r] + bs[nt]);
        }
    }
    gridbar(bar, 1);

    // ================= Phase C: sparse attention =================
    // v9 math: O(1)-scaled scores (q,k ~ N(0,1)) -> no max tracking; softmax
    // is shift-invariant; l += e^s, o += e^s*v. 8 streams per query,
    // half-wave-coalesced KV rows. 4 sequential queries per block.
    {
        const int p = lane >> 5;
        const int h = (lane >> 2) & 7;
        const int s = lane & 3;
        const int koff = h * HD + s * 8;
        const float sc = 0.17677669529663687f;  // 1/sqrt(32)

        for (int qi = 0; qi < 4; ++qi) {
            const int q = b * 4 + qi;

            float qv[8];
            {
                half8 qh = *(const half8*)(Qh + (size_t)q * FDIM + koff);
#pragma unroll
                for (int i = 0; i < 8; ++i) qv[i] = (float)qh[i] * sc;
            }

            float o[8];
#pragma unroll
            for (int i = 0; i < 8; ++i) o[i] = 0.f;
            float l = 0.f;

            const int n = cnt[q];
            const ushort_t* nl = nbr + (size_t)q * CAP;

            for (int j = 2 * wave + p; j < n; j += 8) {
                const int k = nl[j];
                const _Float16* r = KV + ((size_t)k << 9) + koff;
                half8 k8 = *(const half8*)(r);
                half8 v8 = *(const half8*)(r + 256);

                float part = 0.f;
#pragma unroll
                for (int i = 0; i < 8; ++i)
                    part = fmaf(qv[i], (float)k8[i], part);
                part += __shfl_xor(part, 1, 64);
                part += __shfl_xor(part, 2, 64);

                const float pw = __expf(part);
                l += pw;
#pragma unroll
                for (int i = 0; i < 8; ++i)
                    o[i] = fmaf(pw, (float)v8[i], o[i]);
            }

            l += __shfl_xor(l, 32, 64);
#pragma unroll
            for (int i = 0; i < 8; ++i) o[i] += __shfl_xor(o[i], 32, 64);

            if (lane < 32) {  // lane == h*4+s
                float* dst = &sm[wave][lane][0];
                *(float4*)(dst)     = (float4){o[0], o[1], o[2], o[3]};
                *(float4*)(dst + 4) = (float4){o[4], o[5], o[6], o[7]};
                dst[8] = l;
            }
            __syncthreads();

            if (t < 32) {  // t == h*4+s ; output offset = 8*t
                float4 x0 = *(const float4*)&sm[0][t][0];
                float4 x1 = *(const float4*)&sm[0][t][4];
                float O[8] = {x0.x, x0.y, x0.z, x0.w, x1.x, x1.y, x1.z, x1.w};
                float L = sm[0][t][8];
#pragma unroll
                for (int w = 1; w < 4; ++w) {
                    float4 y0 = *(const float4*)&sm[w][t][0];
                    float4 y1 = *(const float4*)&sm[w][t][4];
                    L += sm[w][t][8];
                    O[0] += y0.x; O[1] += y0.y; O[2] += y0.z; O[3] += y0.w;
                    O[4] += y1.x; O[5] += y1.y; O[6] += y1.z; O[7] += y1.w;
                }
                const float inv = 1.0f / L;  // n==0 -> NaN, matches ref
                half8 ho;
#pragma unroll
                for (int i = 0; i < 8; ++i) ho[i] = (_Float16)(O[i] * inv);
                *(half8*)(Ob + (size_t)q * FDIM + t * 8) = ho;
            }
            __syncthreads();  // protect sm reuse by next query
        }
    }
    gridbar(bar, 2);

    // ================= Phase D: O projection =================
    if (b < 256) {
        const int m0 = (b >> 2) * 64;
        const int n0 = (b & 3) * 64;

        f32x4 acc[4];
        mfma_tile_16x64(Ob, cb + CB_WO, m0, n0, wave, lane, acc);

        const int col  = lane & 15;
        const int quad = lane >> 4;
#pragma unroll
        for (int nt = 0; nt < 4; ++nt) {
            const float bb = bo[n0 + nt * 16 + col];
#pragma unroll
            for (int r = 0; r < 4; ++r)
                out[(size_t)(m0 + wave * 16 + quad * 4 + r) * 256 +
                    n0 + nt * 16 + col] = acc[nt][r] + bb;
        }
    }
}

// ---------------------------------------------------------------------------
extern "C" void kernel_launch(void* const* d_in, const int* in_sizes, int n_in,
                              void* d_out, int out_size, void* d_ws, size_t ws_size,
                              hipStream_t stream) {
    const float* cur_feats   = (const float*)d_in[0];
    const float* hist_feats  = (const float*)d_in[1];
    const float* cur_coords  = (const float*)d_in[2];
    const float* hist_coords = (const float*)d_in[3];
    const float* Wq = (const float*)d_in[4];
    const float* bq = (const float*)d_in[5];
    const float* Wk = (const float*)d_in[6];
    const float* bk = (const float*)d_in[7];
    const float* Wv = (const float*)d_in[8];
    const float* bv = (const float*)d_in[9];
    const float* Wo = (const float*)d_in[10];
    const float* bo = (const float*)d_in[11];
    float* out = (float*)d_out;

    char* w = (char*)d_ws;
    _Float16*  Qh  = (_Float16*)(w);                           // 2 MiB
    _Float16*  KV  = (_Float16*)(w + (4 << 20));               // 4 MiB
    ushort_t*  nbr = (ushort_t*)(w + (8 << 20));               // 4 MiB
    int*       cnt = (int*)(w + (12 << 20));                   // 16 KiB
    int*       bar = (int*)(w + (12 << 20) + (32 << 10));      // 256 B
    _Float16*  Ob  = (_Float16*)(w + (12 << 20) + (64 << 10)); // 2 MiB
    _Float16*  cb  = (_Float16*)(w + (15 << 20));              // ~4.5 MiB

    hipMemsetAsync(bar, 0, 256, stream);  // zero barrier state (ws is poisoned)

    fused<<<NBLK, 256, 0, stream>>>(cur_feats, hist_feats, Wq, Wk, Wv, Wo,
                                    cur_coords, hist_coords, bq, bk, bv, bo,
                                    cb, Qh, KV, nbr, cnt, Ob, out, bar);
}

// Round 4
// 208.650 us; speedup vs baseline: 3.0350x; 3.0350x over previous
//
#include <hip/hip_runtime.h>
#include <math.h>

#define FDIM 256
#define NH 8
#define HD 32
#define NQ 4096
#define NKEY 4096
#define CAP 512
#define R2 9.0f

// Diagnostic: repeat the attention body this many times inside one dispatch
// (idempotent). At REP=4, attn surfaces in rocprof's top-5 (>44us fills)
// whenever the real attn time exceeds ~11us, exposing its regime counters.
#define ATTN_REP 4

typedef _Float16 half8 __attribute__((ext_vector_type(8)));
typedef _Float16 half4v __attribute__((ext_vector_type(4)));
typedef float f32x4 __attribute__((ext_vector_type(4)));
typedef unsigned short ushort_t;

// castbuf layout (f16 elements) — weights only now; features are converted
// in-register inside the GEMM (identical single-rounding numerics).
#define CB_WQ   0
#define CB_WK   65536
#define CB_WV   131072
#define CB_WO   196608
#define CB_F4_TOTAL 65536  // 262144 floats / 4

// ---------------------------------------------------------------------------
// prep: blocks [0,1024) build the neighbor lists; blocks [1024,1280) cast the
// four weight matrices fp32->fp16 (one float4 per thread, exact cover).
// ---------------------------------------------------------------------------
__global__ __launch_bounds__(256) void prep(const float* __restrict__ Wq,
                                            const float* __restrict__ Wk,
                                            const float* __restrict__ Wv,
                                            const float* __restrict__ Wo,
                                            _Float16* __restrict__ dst,
                                            const float* __restrict__ qc,
                                            const float* __restrict__ kc,
                                            ushort_t* __restrict__ nbr,
                                            int* __restrict__ cnt) {
    if (blockIdx.x < 1024) {
        // ---- neighbor build: exact reference fp32 op order (no contraction)
        const int q    = blockIdx.x * 4 + (threadIdx.x >> 6);
        const int lane = threadIdx.x & 63;
        const float qx = qc[q * 3 + 0];
        const float qy = qc[q * 3 + 1];
        const float qz = qc[q * 3 + 2];
        int base = 0;
        for (int k0 = 0; k0 < NKEY; k0 += 64) {
            const int k = k0 + lane;
            float dx = __fsub_rn(qx, kc[k * 3 + 0]);
            float dy = __fsub_rn(qy, kc[k * 3 + 1]);
            float dz = __fsub_rn(qz, kc[k * 3 + 2]);
            float d2 = __fadd_rn(__fadd_rn(__fmul_rn(dx, dx), __fmul_rn(dy, dy)),
                                 __fmul_rn(dz, dz));
            bool valid = (d2 <= R2);
            unsigned long long bal = __ballot(valid);
            if (valid) {
                int pos = base + __popcll(bal & ((1ull << lane) - 1ull));
                if (pos < CAP) nbr[(size_t)q * CAP + pos] = (ushort_t)k;
            }
            base += __popcll(bal);
        }
        if (lane == 0) cnt[q] = (base > CAP) ? CAP : base;
    } else {
        // ---- fp32 -> fp16 cast of the weights (65536 float4s, 256 blocks)
        const int i4 = (blockIdx.x - 1024) * 256 + threadIdx.x;
        const float* src;
        int base;
        if (i4 < 16384)      { src = Wq; base = 0; }
        else if (i4 < 32768) { src = Wk; base = 16384; }
        else if (i4 < 49152) { src = Wv; base = 32768; }
        else                 { src = Wo; base = 49152; }
        float4 v = ((const float4*)src)[i4 - base];
        half4v h;
        h[0] = (_Float16)v.x; h[1] = (_Float16)v.y;
        h[2] = (_Float16)v.z; h[3] = (_Float16)v.w;
        ((half4v*)dst)[i4] = h;
    }
}

// ---------------------------------------------------------------------------
// MFMA GEMM cores: C[m][n] = sum_k A[m][k] * W[n][k]  (K=256). Wave tile
// 16x64, no LDS. f32A variant reads A as fp32 and converts in-register
// (saves the feature-cast pass; same single-rounding numerics).
// ---------------------------------------------------------------------------
__device__ __forceinline__ void mfma_tile_16x64_f16A(const _Float16* __restrict__ A,
                                                     const _Float16* __restrict__ W,
                                                     int m0, int n0, int wave, int lane,
                                                     f32x4 acc[4]) {
    const int row  = lane & 15;
    const int quad = lane >> 4;
    const _Float16* aptr = A + (size_t)(m0 + wave * 16 + row) * 256 + quad * 8;
    const _Float16* wptr = W + (size_t)(n0 + row) * 256 + quad * 8;
#pragma unroll
    for (int i = 0; i < 4; ++i) acc[i] = (f32x4){0.f, 0.f, 0.f, 0.f};
#pragma unroll
    for (int k0 = 0; k0 < 8; ++k0) {
        half8 a = *(const half8*)(aptr + k0 * 32);
#pragma unroll
        for (int nt = 0; nt < 4; ++nt) {
            half8 b = *(const half8*)(wptr + (size_t)nt * 16 * 256 + k0 * 32);
            acc[nt] = __builtin_amdgcn_mfma_f32_16x16x32_f16(a, b, acc[nt], 0, 0, 0);
        }
    }
}

__device__ __forceinline__ void mfma_tile_16x64_f32A(const float* __restrict__ A,
                                                     const _Float16* __restrict__ W,
                                                     int m0, int n0, int wave, int lane,
                                                     f32x4 acc[4]) {
    const int row  = lane & 15;
    const int quad = lane >> 4;
    const float* aptr = A + (size_t)(m0 + wave * 16 + row) * 256 + quad * 8;
    const _Float16* wptr = W + (size_t)(n0 + row) * 256 + quad * 8;
#pragma unroll
    for (int i = 0; i < 4; ++i) acc[i] = (f32x4){0.f, 0.f, 0.f, 0.f};
#pragma unroll
    for (int k0 = 0; k0 < 8; ++k0) {
        float4 a0 = *(const float4*)(aptr + k0 * 32);
        float4 a1 = *(const float4*)(aptr + k0 * 32 + 4);
        half8 a;
        a[0] = (_Float16)a0.x; a[1] = (_Float16)a0.y;
        a[2] = (_Float16)a0.z; a[3] = (_Float16)a0.w;
        a[4] = (_Float16)a1.x; a[5] = (_Float16)a1.y;
        a[6] = (_Float16)a1.z; a[7] = (_Float16)a1.w;
#pragma unroll
        for (int nt = 0; nt < 4; ++nt) {
            half8 b = *(const half8*)(wptr + (size_t)nt * 16 * 256 + k0 * 32);
            acc[nt] = __builtin_amdgcn_mfma_f32_16x16x32_f16(a, b, acc[nt], 0, 0, 0);
        }
    }
}

// Fused QKV. z=0: Q f16 out (row-major [q][256]). z=1/2: K/V f16 into
// row-major interleaved KV[k][0:256]=K, KV[k][256:512]=V. A is fp32 feats.
__global__ __launch_bounds__(256) void qkv_mfma(const float* __restrict__ cur,
                                                const float* __restrict__ histf,
                                                const _Float16* __restrict__ cb,
                                                const float* __restrict__ bq,
                                                const float* __restrict__ bk,
                                                const float* __restrict__ bv,
                                                _Float16* __restrict__ Qh,
                                                _Float16* __restrict__ KV) {
    const int z    = blockIdx.z;
    const int wave = threadIdx.x >> 6;
    const int lane = threadIdx.x & 63;
    const int m0   = blockIdx.y * 64;
    const int n0   = blockIdx.x * 64;

    const float* A = (z == 0) ? cur : histf;
    const _Float16* W = (z == 0) ? (cb + CB_WQ) : (z == 1) ? (cb + CB_WK) : (cb + CB_WV);
    const float* bias = (z == 0) ? bq : (z == 1) ? bk : bv;

    f32x4 acc[4];
    mfma_tile_16x64_f32A(A, W, m0, n0, wave, lane, acc);

    const int col  = lane & 15;
    const int quad = lane >> 4;
    float bs[4];
#pragma unroll
    for (int nt = 0; nt < 4; ++nt) bs[nt] = bias[n0 + nt * 16 + col];

    if (z == 0) {
#pragma unroll
        for (int nt = 0; nt < 4; ++nt)
#pragma unroll
            for (int r = 0; r < 4; ++r)
                Qh[(size_t)(m0 + wave * 16 + quad * 4 + r) * 256 + n0 + nt * 16 + col] =
                    (_Float16)(acc[nt][r] + bs[nt]);
    } else {
        const int off = (z == 1) ? 0 : 256;
#pragma unroll
        for (int nt = 0; nt < 4; ++nt)
#pragma unroll
            for (int r = 0; r < 4; ++r)
                KV[(size_t)(m0 + wave * 16 + quad * 4 + r) * 512 + off + n0 + nt * 16 + col] =
                    (_Float16)(acc[nt][r] + bs[nt]);
    }
}

// O-projection: out fp32 = Ob_f16 * Wo_f16^T + bo
__global__ __launch_bounds__(256) void o_mfma(const _Float16* __restrict__ Ob,
                                              const _Float16* __restrict__ Wo,
                                              const float* __restrict__ bo,
                                              float* __restrict__ out) {
    const int wave = threadIdx.x >> 6;
    const int lane = threadIdx.x & 63;
    const int m0   = blockIdx.y * 64;
    const int n0   = blockIdx.x * 64;

    f32x4 acc[4];
    mfma_tile_16x64_f16A(Ob, Wo, m0, n0, wave, lane, acc);

    const int col  = lane & 15;
    const int quad = lane >> 4;
#pragma unroll
    for (int nt = 0; nt < 4; ++nt) {
        const float b = bo[n0 + nt * 16 + col];
#pragma unroll
        for (int r = 0; r < 4; ++r)
            out[(size_t)(m0 + wave * 16 + quad * 4 + r) * 256 + n0 + nt * 16 + col] =
                acc[nt][r] + b;
    }
}

// ---------------------------------------------------------------------------
// Sparse attention v9 body, repeated ATTN_REP times (diagnostic
// amplification; idempotent). asm memory clobber per rep prevents CSE of
// repeats. Math unchanged: shift-free softmax (scores O(1)), 8 neighbor
// streams (wave x half-wave), half-wave-coalesced 1KB KV rows.
// ---------------------------------------------------------------------------
__global__ __launch_bounds__(256) void sparse_attn9x4(const _Float16* __restrict__ Qh,
                                                      const _Float16* __restrict__ KV,
                                                      const ushort_t* __restrict__ nbr,
                                                      const int* __restrict__ cnt,
                                                      _Float16* __restrict__ Ob) {
    __shared__ float sm[4][32][12];
    const int q    = blockIdx.x;
    const int t    = threadIdx.x;
    const int wave = t >> 6;
    const int lane = t & 63;
    const int p    = lane >> 5;
    const int h    = (lane >> 2) & 7;
    const int s    = lane & 3;
    const int koff = h * HD + s * 8;

    for (int rep = 0; rep < ATTN_REP; ++rep) {
        asm volatile("" ::: "memory");  // keep each rep's loads/stores live

        float qv[8];
        {
            half8 qh = *(const half8*)(Qh + (size_t)q * FDIM + koff);
            const float sc = 0.17677669529663687f;
#pragma unroll
            for (int i = 0; i < 8; ++i) qv[i] = (float)qh[i] * sc;
        }

        float o[8];
#pragma unroll
        for (int i = 0; i < 8; ++i) o[i] = 0.f;
        float l = 0.f;

        const int n = cnt[q];
        const ushort_t* nl = nbr + (size_t)q * CAP;

        for (int j = 2 * wave + p; j < n; j += 8) {
            const int k = nl[j];
            const _Float16* r = KV + ((size_t)k << 9) + koff;
            half8 k8 = *(const half8*)(r);
            half8 v8 = *(const half8*)(r + 256);

            float part = 0.f;
#pragma unroll
            for (int i = 0; i < 8; ++i)
                part = fmaf(qv[i], (float)k8[i], part);
            part += __shfl_xor(part, 1, 64);
            part += __shfl_xor(part, 2, 64);

            const float pw = __expf(part);
            l += pw;
#pragma unroll
            for (int i = 0; i < 8; ++i)
                o[i] = fmaf(pw, (float)v8[i], o[i]);
        }

        l += __shfl_xor(l, 32, 64);
#pragma unroll
        for (int i = 0; i < 8; ++i) o[i] += __shfl_xor(o[i], 32, 64);

        if (lane < 32) {  // lane == h*4+s
            float* dst = &sm[wave][lane][0];
            *(float4*)(dst)     = (float4){o[0], o[1], o[2], o[3]};
            *(float4*)(dst + 4) = (float4){o[4], o[5], o[6], o[7]};
            dst[8] = l;
        }
        __syncthreads();

        if (t < 32) {  // t == h*4+s ; output offset = 8*t
            float4 x0 = *(const float4*)&sm[0][t][0];
            float4 x1 = *(const float4*)&sm[0][t][4];
            float O[8] = {x0.x, x0.y, x0.z, x0.w, x1.x, x1.y, x1.z, x1.w};
            float L = sm[0][t][8];
#pragma unroll
            for (int w = 1; w < 4; ++w) {
                float4 y0 = *(const float4*)&sm[w][t][0];
                float4 y1 = *(const float4*)&sm[w][t][4];
                L += sm[w][t][8];
                O[0] += y0.x; O[1] += y0.y; O[2] += y0.z; O[3] += y0.w;
                O[4] += y1.x; O[5] += y1.y; O[6] += y1.z; O[7] += y1.w;
            }
            const float inv = 1.0f / L;  // n==0 -> L==0 -> inf -> NaN, matches ref
            half8 ho;
#pragma unroll
            for (int i = 0; i < 8; ++i) ho[i] = (_Float16)(O[i] * inv);
            *(half8*)(Ob + (size_t)q * FDIM + t * 8) = ho;
        }
        __syncthreads();  // sm safe for next rep
    }
}

// ---------------------------------------------------------------------------
extern "C" void kernel_launch(void* const* d_in, const int* in_sizes, int n_in,
                              void* d_out, int out_size, void* d_ws, size_t ws_size,
                              hipStream_t stream) {
    const float* cur_feats   = (const float*)d_in[0];
    const float* hist_feats  = (const float*)d_in[1];
    const float* cur_coords  = (const float*)d_in[2];
    const float* hist_coords = (const float*)d_in[3];
    const float* bq = (const float*)d_in[5];
    const float* bk = (const float*)d_in[7];
    const float* bv = (const float*)d_in[9];
    const float* bo = (const float*)d_in[11];
    float* out = (float*)d_out;

    char* w = (char*)d_ws;
    _Float16*  Qh  = (_Float16*)(w);                           // 2 MiB
    _Float16*  KV  = (_Float16*)(w + (4 << 20));               // 4 MiB
    ushort_t*  nbr = (ushort_t*)(w + (8 << 20));               // 4 MiB
    int*       cnt = (int*)(w + (12 << 20));                   // 16 KiB
    _Float16*  Ob  = (_Float16*)(w + (12 << 20) + (64 << 10)); // 2 MiB
    _Float16*  cb  = (_Float16*)(w + (15 << 20));              // 512 KiB (weights f16)

    prep<<<1280, 256, 0, stream>>>((const float*)d_in[4], (const float*)d_in[6],
                                   (const float*)d_in[8], (const float*)d_in[10], cb,
                                   cur_coords, hist_coords, nbr, cnt);

    qkv_mfma<<<dim3(4, 64, 3), 256, 0, stream>>>(cur_feats, hist_feats, cb,
                                                 bq, bk, bv, Qh, KV);

    sparse_attn9x4<<<NQ, 256, 0, stream>>>(Qh, KV, nbr, cnt, Ob);

    o_mfma<<<dim3(4, 64), 256, 0, stream>>>(Ob, cb + CB_WO, bo, out);
}

// Round 5
// 159.073 us; speedup vs baseline: 3.9809x; 1.3117x over previous
//
#include <hip/hip_runtime.h>
#include <math.h>

#define FDIM 256
#define NH 8
#define HD 32
#define NQ 4096
#define NKEY 4096
#define CAP 512
#define R2 9.0f

typedef _Float16 half8 __attribute__((ext_vector_type(8)));
typedef _Float16 half2v __attribute__((ext_vector_type(2)));
typedef float f32x4 __attribute__((ext_vector_type(4)));
typedef unsigned short ushort_t;

// ---------------------------------------------------------------------------
// MFMA GEMM cores: C[m][n] = sum_k A[m][k] * W[n][k]  (K=256). Wave tile
// 16x64, no LDS. Both A and W are loaded fp32 and converted in-register
// (single f32->f16 RN rounding — numerically identical to a cast pass, and
// it removes the cast kernel + the prep->qkv dependency entirely).
// ---------------------------------------------------------------------------
__device__ __forceinline__ void mfma_tile_16x64_f32AW(const float* __restrict__ A,
                                                      const float* __restrict__ W,
                                                      int m0, int n0, int wave, int lane,
                                                      f32x4 acc[4]) {
    const int row  = lane & 15;
    const int quad = lane >> 4;
    const float* aptr = A + (size_t)(m0 + wave * 16 + row) * 256 + quad * 8;
    const float* wptr = W + (size_t)(n0 + row) * 256 + quad * 8;
#pragma unroll
    for (int i = 0; i < 4; ++i) acc[i] = (f32x4){0.f, 0.f, 0.f, 0.f};
#pragma unroll
    for (int k0 = 0; k0 < 8; ++k0) {
        float4 a0 = *(const float4*)(aptr + k0 * 32);
        float4 a1 = *(const float4*)(aptr + k0 * 32 + 4);
        half8 a;
        a[0] = (_Float16)a0.x; a[1] = (_Float16)a0.y;
        a[2] = (_Float16)a0.z; a[3] = (_Float16)a0.w;
        a[4] = (_Float16)a1.x; a[5] = (_Float16)a1.y;
        a[6] = (_Float16)a1.z; a[7] = (_Float16)a1.w;
#pragma unroll
        for (int nt = 0; nt < 4; ++nt) {
            float4 b0 = *(const float4*)(wptr + (size_t)nt * 16 * 256 + k0 * 32);
            float4 b1 = *(const float4*)(wptr + (size_t)nt * 16 * 256 + k0 * 32 + 4);
            half8 b;
            b[0] = (_Float16)b0.x; b[1] = (_Float16)b0.y;
            b[2] = (_Float16)b0.z; b[3] = (_Float16)b0.w;
            b[4] = (_Float16)b1.x; b[5] = (_Float16)b1.y;
            b[6] = (_Float16)b1.z; b[7] = (_Float16)b1.w;
            acc[nt] = __builtin_amdgcn_mfma_f32_16x16x32_f16(a, b, acc[nt], 0, 0, 0);
        }
    }
}

// A is f16 (attn output Ob), W is fp32 (Wo direct).
__device__ __forceinline__ void mfma_tile_16x64_f16A_f32W(const _Float16* __restrict__ A,
                                                          const float* __restrict__ W,
                                                          int m0, int n0, int wave, int lane,
                                                          f32x4 acc[4]) {
    const int row  = lane & 15;
    const int quad = lane >> 4;
    const _Float16* aptr = A + (size_t)(m0 + wave * 16 + row) * 256 + quad * 8;
    const float* wptr = W + (size_t)(n0 + row) * 256 + quad * 8;
#pragma unroll
    for (int i = 0; i < 4; ++i) acc[i] = (f32x4){0.f, 0.f, 0.f, 0.f};
#pragma unroll
    for (int k0 = 0; k0 < 8; ++k0) {
        half8 a = *(const half8*)(aptr + k0 * 32);
#pragma unroll
        for (int nt = 0; nt < 4; ++nt) {
            float4 b0 = *(const float4*)(wptr + (size_t)nt * 16 * 256 + k0 * 32);
            float4 b1 = *(const float4*)(wptr + (size_t)nt * 16 * 256 + k0 * 32 + 4);
            half8 b;
            b[0] = (_Float16)b0.x; b[1] = (_Float16)b0.y;
            b[2] = (_Float16)b0.z; b[3] = (_Float16)b0.w;
            b[4] = (_Float16)b1.x; b[5] = (_Float16)b1.y;
            b[6] = (_Float16)b1.z; b[7] = (_Float16)b1.w;
            acc[nt] = __builtin_amdgcn_mfma_f32_16x16x32_f16(a, b, acc[nt], 0, 0, 0);
        }
    }
}

// ---------------------------------------------------------------------------
// Merged prep+QKV: one launch, two independent block families (no barrier
// needed — neighbor lists and QKV GEMMs share no data).
//   blocks [0,768):    QKV projection tiles (z = b>>8; 64x64 tile each)
//   blocks [768,1792): neighbor-list build (4 queries per block)
// QKV tiles go first (longer pole) so they dispatch earliest.
// ---------------------------------------------------------------------------
__global__ __launch_bounds__(256) void prep_qkv(const float* __restrict__ cur,
                                                const float* __restrict__ histf,
                                                const float* __restrict__ Wq,
                                                const float* __restrict__ Wk,
                                                const float* __restrict__ Wv,
                                                const float* __restrict__ qc,
                                                const float* __restrict__ kc,
                                                const float* __restrict__ bq,
                                                const float* __restrict__ bk,
                                                const float* __restrict__ bv,
                                                _Float16* __restrict__ Qh,
                                                _Float16* __restrict__ KV,
                                                ushort_t* __restrict__ nbr,
                                                int* __restrict__ cnt) {
    const int b    = blockIdx.x;
    const int wave = threadIdx.x >> 6;
    const int lane = threadIdx.x & 63;

    if (b < 768) {
        const int z   = b >> 8;        // 0:Q 1:K 2:V
        const int rem = b & 255;
        const int m0  = (rem >> 2) * 64;
        const int n0  = (rem & 3) * 64;

        const float* A    = (z == 0) ? cur : histf;
        const float* W    = (z == 0) ? Wq : (z == 1) ? Wk : Wv;
        const float* bias = (z == 0) ? bq : (z == 1) ? bk : bv;

        f32x4 acc[4];
        mfma_tile_16x64_f32AW(A, W, m0, n0, wave, lane, acc);

        const int col  = lane & 15;
        const int quad = lane >> 4;
        float bs[4];
#pragma unroll
        for (int nt = 0; nt < 4; ++nt) bs[nt] = bias[n0 + nt * 16 + col];

        if (z == 0) {
#pragma unroll
            for (int nt = 0; nt < 4; ++nt)
#pragma unroll
                for (int r = 0; r < 4; ++r)
                    Qh[(size_t)(m0 + wave * 16 + quad * 4 + r) * 256 +
                       n0 + nt * 16 + col] = (_Float16)(acc[nt][r] + bs[nt]);
        } else {
            const int off = (z == 1) ? 0 : 256;
#pragma unroll
            for (int nt = 0; nt < 4; ++nt)
#pragma unroll
                for (int r = 0; r < 4; ++r)
                    KV[(size_t)(m0 + wave * 16 + quad * 4 + r) * 512 + off +
                       n0 + nt * 16 + col] = (_Float16)(acc[nt][r] + bs[nt]);
        }
    } else {
        // ---- neighbor build: exact reference fp32 op order (no contraction)
        const int q  = (b - 768) * 4 + wave;
        const float qx = qc[q * 3 + 0];
        const float qy = qc[q * 3 + 1];
        const float qz = qc[q * 3 + 2];
        int base = 0;
        for (int k0 = 0; k0 < NKEY; k0 += 64) {
            const int k = k0 + lane;
            float dx = __fsub_rn(qx, kc[k * 3 + 0]);
            float dy = __fsub_rn(qy, kc[k * 3 + 1]);
            float dz = __fsub_rn(qz, kc[k * 3 + 2]);
            float d2 = __fadd_rn(__fadd_rn(__fmul_rn(dx, dx), __fmul_rn(dy, dy)),
                                 __fmul_rn(dz, dz));
            bool valid = (d2 <= R2);
            unsigned long long bal = __ballot(valid);
            if (valid) {
                int pos = base + __popcll(bal & ((1ull << lane) - 1ull));
                if (pos < CAP) nbr[(size_t)q * CAP + pos] = (ushort_t)k;
            }
            base += __popcll(bal);
        }
        if (lane == 0) cnt[q] = (base > CAP) ? CAP : base;
    }
}

// ---------------------------------------------------------------------------
// Sparse attention v11: v9 structure (8 neighbor streams, shift-free
// softmax, half-wave-coalesced 1KB KV rows) with the score dot computed via
// v_dot2_f32_f16 (2 MACs/instr, f32 accumulate) and 1/sqrt(HD) deferred to
// after the cross-lane reduce (one mul; matches ref's "dot then scale").
// Cuts per-neighbor VALU ~40 -> ~28 (attn was 47% VALUBusy, issue-bound).
// ---------------------------------------------------------------------------
__global__ __launch_bounds__(256) void sparse_attn11(const _Float16* __restrict__ Qh,
                                                     const _Float16* __restrict__ KV,
                                                     const ushort_t* __restrict__ nbr,
                                                     const int* __restrict__ cnt,
                                                     _Float16* __restrict__ Ob) {
    __shared__ float sm[4][32][12];
    const int q    = blockIdx.x;
    const int t    = threadIdx.x;
    const int wave = t >> 6;
    const int lane = t & 63;
    const int p    = lane >> 5;
    const int h    = (lane >> 2) & 7;
    const int s    = lane & 3;
    const int koff = h * HD + s * 8;
    const float sc = 0.17677669529663687f;  // 1/sqrt(32)

    // 8-dim q slice for (h,s), kept as raw f16 pairs (dot2 operand)
    const half8 qh = *(const half8*)(Qh + (size_t)q * FDIM + koff);

    float o[8];
#pragma unroll
    for (int i = 0; i < 8; ++i) o[i] = 0.f;
    float l = 0.f;

    const int n = cnt[q];
    const ushort_t* nl = nbr + (size_t)q * CAP;

    for (int j = 2 * wave + p; j < n; j += 8) {
        const int k = nl[j];
        const _Float16* r = KV + ((size_t)k << 9) + koff;
        half8 k8 = *(const half8*)(r);
        half8 v8 = *(const half8*)(r + 256);

        float part = 0.f;
#pragma unroll
        for (int i = 0; i < 4; ++i) {
            half2v qa, ka;
            qa[0] = qh[2 * i]; qa[1] = qh[2 * i + 1];
            ka[0] = k8[2 * i]; ka[1] = k8[2 * i + 1];
#if defined(__has_builtin) && __has_builtin(__builtin_amdgcn_fdot2)
            part = __builtin_amdgcn_fdot2(qa, ka, part, false);
#else
            part = fmaf((float)qa[0], (float)ka[0], part);
            part = fmaf((float)qa[1], (float)ka[1], part);
#endif
        }
        // full 32-dim score: reduce across the 4 s-lanes of this head
        part += __shfl_xor(part, 1, 64);
        part += __shfl_xor(part, 2, 64);

        const float pw = __expf(part * sc);
        l += pw;
#pragma unroll
        for (int i = 0; i < 8; ++i)
            o[i] = fmaf(pw, (float)v8[i], o[i]);  // f32 accum (fma_mix)
    }

    // merge the two 32-lane halves (plain sums)
    l += __shfl_xor(l, 32, 64);
#pragma unroll
    for (int i = 0; i < 8; ++i) o[i] += __shfl_xor(o[i], 32, 64);

    if (lane < 32) {  // lane == h*4+s
        float* dst = &sm[wave][lane][0];
        *(float4*)(dst)     = (float4){o[0], o[1], o[2], o[3]};
        *(float4*)(dst + 4) = (float4){o[4], o[5], o[6], o[7]};
        dst[8] = l;
    }
    __syncthreads();

    if (t < 32) {  // t == h*4+s ; output offset = 8*t
        float4 x0 = *(const float4*)&sm[0][t][0];
        float4 x1 = *(const float4*)&sm[0][t][4];
        float O[8] = {x0.x, x0.y, x0.z, x0.w, x1.x, x1.y, x1.z, x1.w};
        float L = sm[0][t][8];
#pragma unroll
        for (int w = 1; w < 4; ++w) {
            float4 y0 = *(const float4*)&sm[w][t][0];
            float4 y1 = *(const float4*)&sm[w][t][4];
            L += sm[w][t][8];
            O[0] += y0.x; O[1] += y0.y; O[2] += y0.z; O[3] += y0.w;
            O[4] += y1.x; O[5] += y1.y; O[6] += y1.z; O[7] += y1.w;
        }
        const float inv = 1.0f / L;  // n==0 -> L==0 -> inf -> NaN, matches ref
        half8 ho;
#pragma unroll
        for (int i = 0; i < 8; ++i) ho[i] = (_Float16)(O[i] * inv);
        *(half8*)(Ob + (size_t)q * FDIM + t * 8) = ho;
    }
}

// O-projection: out fp32 = Ob_f16 * (f16)Wo^T + bo  (Wo converted in-register)
__global__ __launch_bounds__(256) void o_mfma(const _Float16* __restrict__ Ob,
                                              const float* __restrict__ Wo,
                                              const float* __restrict__ bo,
                                              float* __restrict__ out) {
    const int wave = threadIdx.x >> 6;
    const int lane = threadIdx.x & 63;
    const int m0   = blockIdx.y * 64;
    const int n0   = blockIdx.x * 64;

    f32x4 acc[4];
    mfma_tile_16x64_f16A_f32W(Ob, Wo, m0, n0, wave, lane, acc);

    const int col  = lane & 15;
    const int quad = lane >> 4;
#pragma unroll
    for (int nt = 0; nt < 4; ++nt) {
        const float b = bo[n0 + nt * 16 + col];
#pragma unroll
        for (int r = 0; r < 4; ++r)
            out[(size_t)(m0 + wave * 16 + quad * 4 + r) * 256 + n0 + nt * 16 + col] =
                acc[nt][r] + b;
    }
}

// ---------------------------------------------------------------------------
extern "C" void kernel_launch(void* const* d_in, const int* in_sizes, int n_in,
                              void* d_out, int out_size, void* d_ws, size_t ws_size,
                              hipStream_t stream) {
    const float* cur_feats   = (const float*)d_in[0];
    const float* hist_feats  = (const float*)d_in[1];
    const float* cur_coords  = (const float*)d_in[2];
    const float* hist_coords = (const float*)d_in[3];
    const float* Wq = (const float*)d_in[4];
    const float* bq = (const float*)d_in[5];
    const float* Wk = (const float*)d_in[6];
    const float* bk = (const float*)d_in[7];
    const float* Wv = (const float*)d_in[8];
    const float* bv = (const float*)d_in[9];
    const float* Wo = (const float*)d_in[10];
    const float* bo = (const float*)d_in[11];
    float* out = (float*)d_out;

    char* w = (char*)d_ws;
    _Float16*  Qh  = (_Float16*)(w);                           // 2 MiB
    _Float16*  KV  = (_Float16*)(w + (4 << 20));               // 4 MiB
    ushort_t*  nbr = (ushort_t*)(w + (8 << 20));               // 4 MiB
    int*       cnt = (int*)(w + (12 << 20));                   // 16 KiB
    _Float16*  Ob  = (_Float16*)(w + (12 << 20) + (64 << 10)); // 2 MiB

    prep_qkv<<<1792, 256, 0, stream>>>(cur_feats, hist_feats, Wq, Wk, Wv,
                                       cur_coords, hist_coords, bq, bk, bv,
                                       Qh, KV, nbr, cnt);

    sparse_attn11<<<NQ, 256, 0, stream>>>(Qh, KV, nbr, cnt, Ob);

    o_mfma<<<dim3(4, 64), 256, 0, stream>>>(Ob, Wo, bo, out);
}